// Round 16
// baseline (210.765 us; speedup 1.0000x reference)
//
#include <hip/hip_runtime.h>
#include <cmath>

#define BATCH 8
#define SEQLEN 4096
#define DMODEL 192
#define DINNER 384
#define DSTATE 16
#define DTRANK 12
#define XSTR 64            // padded x_dbl row stride (44 real cols)
#define MTOT (BATCH*SEQLEN)
#define CH 16              // scan chunk length
#define NC (SEQLEN/CH)     // 256 chunks

typedef __bf16 bf16x8 __attribute__((ext_vector_type(8)));
typedef float f32x4 __attribute__((ext_vector_type(4)));
typedef float f32x2 __attribute__((ext_vector_type(2)));
typedef unsigned short us8 __attribute__((ext_vector_type(8)));

__device__ __forceinline__ float silu_f(float x) { return x / (1.f + __expf(-x)); }
__device__ __forceinline__ unsigned short f2bf(float f) {
  unsigned u = __float_as_uint(f);
  return (unsigned short)((u + 0x7FFF + ((u >> 16) & 1)) >> 16);   // RNE
}
__device__ __forceinline__ float bf2f(unsigned short b) {
  return __uint_as_float(((unsigned)b) << 16);
}

// packed fp32 (VOP3P)
__device__ __forceinline__ f32x2 pk_mul(f32x2 a, f32x2 b) {
  f32x2 d; asm("v_pk_mul_f32 %0, %1, %2" : "=v"(d) : "v"(a), "v"(b)); return d;
}
__device__ __forceinline__ f32x2 pk_fma(f32x2 a, f32x2 b, f32x2 c) {
  f32x2 d; asm("v_pk_fma_f32 %0, %1, %2, %3" : "=v"(d) : "v"(a), "v"(b), "v"(c)); return d;
}

// av2[j] = {e1^(2j+1), e1^(2j+2)}; 1 scalar mul + 7 pk_mul
#define POW16P(av2, e1)                                                     \
  { const float e2s_ = (e1) * (e1);                                         \
    av2[0] = (f32x2){(e1), e2s_};                                           \
    const f32x2 e2b_ = (f32x2){e2s_, e2s_};                                 \
    av2[1] = pk_mul(av2[0], e2b_);                                          \
    const float e4_ = av2[1].y;                                             \
    const f32x2 e4b_ = (f32x2){e4_, e4_};                                   \
    av2[2] = pk_mul(av2[0], e4b_);                                          \
    av2[3] = pk_mul(av2[1], e4b_);                                          \
    const float e8_ = av2[3].y;                                             \
    const f32x2 e8b_ = (f32x2){e8_, e8_};                                   \
    av2[4] = pk_mul(av2[0], e8b_);                                          \
    av2[5] = pk_mul(av2[1], e8b_);                                          \
    av2[6] = pk_mul(av2[2], e8b_);                                          \
    av2[7] = pk_mul(av2[3], e8b_); }

// prep: cast in_proj_w, pad+cast x_proj_w, cast out_proj_w, TRANSPOSE dt_proj_w
__global__ __launch_bounds__(256) void prep_k(const float* __restrict__ in_w,
                                              const float* __restrict__ xw,
                                              const float* __restrict__ ow,
                                              const float* __restrict__ dtw,
                                              unsigned short* __restrict__ wb,
                                              unsigned short* __restrict__ wxb,
                                              unsigned short* __restrict__ owb,
                                              float* __restrict__ dtwt) {
  const int i = blockIdx.x * 256 + threadIdx.x;
  if (i < 768 * DMODEL) wb[i] = f2bf(in_w[i]);
  if (i < XSTR * DINNER) wxb[i] = (i < 44 * DINNER) ? f2bf(xw[i]) : (unsigned short)0;
  if (i < DMODEL * DINNER) owb[i] = f2bf(ow[i]);
  if (i < DTRANK * DINNER) dtwt[i] = dtw[(i % DINNER) * DTRANK + (i / DINNER)];
}

// in_proj: [M][768] = hs[M][192] @ in_w^T. BM=128 BN=128 BK=32, XCD-chunked swizzle.
__global__ __launch_bounds__(256) void gemm_in(const float* __restrict__ hs,
                                               const unsigned short* __restrict__ wb,
                                               unsigned short* __restrict__ xb,
                                               unsigned short* __restrict__ zb) {
  __shared__ unsigned short Als[128 * 40];   // 80B rows
  __shared__ unsigned short Bls[128 * 40];
  const int tid = threadIdx.x;
  const int bid = blockIdx.y * 6 + blockIdx.x;        // 0..1535
  const int lid = (bid & 7) * 192 + (bid >> 3);       // bijective (1536%8==0)
  const int m0 = (lid / 6) * 128, n0 = (lid % 6) * 128;
  const int w = tid >> 6, l = tid & 63;
  const int wm = (w >> 1) * 64, wn = (w & 1) * 64;
  const int lr = l & 15, lk8 = (l >> 4) * 8;
  const int ar = tid >> 1, ag = (tid & 1) * 16;
  const float* Ap = hs + (size_t)(m0 + ar) * DMODEL + ag;
  const unsigned short* Wp = wb + (size_t)(n0 + ar) * DMODEL + ag;
  f32x4 acc[4][4];
#pragma unroll
  for (int i = 0; i < 4; i++)
#pragma unroll
    for (int j = 0; j < 4; j++) acc[i][j] = (f32x4){0.f, 0.f, 0.f, 0.f};
#pragma unroll
  for (int k0 = 0; k0 < DMODEL; k0 += 32) {
    float4 f0 = *(const float4*)(Ap + k0);
    float4 f1 = *(const float4*)(Ap + k0 + 4);
    float4 f2 = *(const float4*)(Ap + k0 + 8);
    float4 f3 = *(const float4*)(Ap + k0 + 12);
    us8 b0 = *(const us8*)(Wp + k0);
    us8 b1 = *(const us8*)(Wp + k0 + 8);
    us8 a0, a1;
    a0[0] = f2bf(f0.x); a0[1] = f2bf(f0.y); a0[2] = f2bf(f0.z); a0[3] = f2bf(f0.w);
    a0[4] = f2bf(f1.x); a0[5] = f2bf(f1.y); a0[6] = f2bf(f1.z); a0[7] = f2bf(f1.w);
    a1[0] = f2bf(f2.x); a1[1] = f2bf(f2.y); a1[2] = f2bf(f2.z); a1[3] = f2bf(f2.w);
    a1[4] = f2bf(f3.x); a1[5] = f2bf(f3.y); a1[6] = f2bf(f3.z); a1[7] = f2bf(f3.w);
    __syncthreads();
    *(us8*)(&Als[ar * 40 + ag]) = a0;
    *(us8*)(&Als[ar * 40 + ag + 8]) = a1;
    *(us8*)(&Bls[ar * 40 + ag]) = b0;
    *(us8*)(&Bls[ar * 40 + ag + 8]) = b1;
    __syncthreads();
    bf16x8 bfr[4];
#pragma unroll
    for (int fn = 0; fn < 4; fn++)
      bfr[fn] = *(const bf16x8*)(&Bls[(wn + fn * 16 + lr) * 40 + lk8]);
#pragma unroll
    for (int fm = 0; fm < 4; fm++) {
      bf16x8 af = *(const bf16x8*)(&Als[(wm + fm * 16 + lr) * 40 + lk8]);
#pragma unroll
      for (int fn = 0; fn < 4; fn++)
        acc[fm][fn] = __builtin_amdgcn_mfma_f32_16x16x32_bf16(af, bfr[fn], acc[fm][fn], 0, 0, 0);
    }
  }
  const int r0 = (l >> 4) * 4;   // C/D: col=lane&15, row=(lane>>4)*4+reg
  unsigned short* dst = (n0 < DINNER) ? xb : zb;
  const int cb0 = (n0 < DINNER) ? n0 : (n0 - DINNER);
#pragma unroll
  for (int fm = 0; fm < 4; fm++) {
    const size_t rowb = (size_t)(m0 + wm + fm * 16 + r0);
#pragma unroll
    for (int fn = 0; fn < 4; fn++) {
      const int col = cb0 + wn + fn * 16 + lr;
#pragma unroll
      for (int r = 0; r < 4; r++)
        dst[(rowb + r) * DINNER + col] = f2bf(acc[fm][fn][r]);
    }
  }
}

// depthwise conv (k=3, same-pad) + SiLU, bf16 in/out, 8 channels/thread
__global__ __launch_bounds__(256) void conv_silu_k(const unsigned short* __restrict__ xb,
                                                   const float* __restrict__ cw,
                                                   const float* __restrict__ cb,
                                                   unsigned short* __restrict__ u16) {
  __shared__ float cws[DINNER * 4];   // [0..3*384) = cw, [3*384..) = cb
  const int tid = threadIdx.x;
  for (int i = tid; i < DINNER * 4; i += 256)
    cws[i] = (i < DINNER * 3) ? cw[i] : cb[i - DINNER * 3];
  __syncthreads();
  const int idx = blockIdx.x * 256 + tid;
  const int d = (idx % 48) * 8;
  const int m = idx / 48;
  const int l = m % SEQLEN;
  const us8 c0 = *(const us8*)(xb + (size_t)m * DINNER + d);
  const bool hm = (l > 0), hp = (l < SEQLEN - 1);
  us8 cm = c0, cp = c0;
  if (hm) cm = *(const us8*)(xb + (size_t)(m - 1) * DINNER + d);
  if (hp) cp = *(const us8*)(xb + (size_t)(m + 1) * DINNER + d);
  us8 o;
#pragma unroll
  for (int j = 0; j < 8; j++) {
    const int dj = d + j;
    float s = cws[DINNER * 3 + dj] + cws[dj * 3 + 1] * bf2f(c0[j]);
    if (hm) s += cws[dj * 3 + 0] * bf2f(cm[j]);
    if (hp) s += cws[dj * 3 + 2] * bf2f(cp[j]);
    o[j] = f2bf(silu_f(s));
  }
  *(us8*)(u16 + (size_t)m * DINNER + d) = o;
}

// x_proj: xdbl[M][64] fp32 = u16[M][384] @ wxb[64][384]^T (bf16 MFMA, fp32 acc)
__global__ __launch_bounds__(256) void xproj_mfma(const unsigned short* __restrict__ u16,
                                                  const unsigned short* __restrict__ wxb,
                                                  float* __restrict__ xdbl) {
  __shared__ unsigned short Als[64 * 40];
  __shared__ unsigned short Bls[64 * 40];
  const int tid = threadIdx.x;
  const int m0 = blockIdx.x * 64;
  const int w = tid >> 6, l = tid & 63;
  const int wm = (w >> 1) * 32, wn = (w & 1) * 32;
  const int lr = l & 15, lk8 = (l >> 4) * 8;
  const int ar = tid >> 2, ag = (tid & 3) * 8;
  const unsigned short* Ap = u16 + (size_t)(m0 + ar) * DINNER + ag;
  const unsigned short* Wp = wxb + (size_t)ar * DINNER + ag;
  f32x4 acc[2][2];
#pragma unroll
  for (int i = 0; i < 2; i++)
#pragma unroll
    for (int j = 0; j < 2; j++) acc[i][j] = (f32x4){0.f, 0.f, 0.f, 0.f};
#pragma unroll
  for (int k0 = 0; k0 < DINNER; k0 += 32) {
    us8 a0 = *(const us8*)(Ap + k0);
    us8 b0 = *(const us8*)(Wp + k0);
    __syncthreads();
    *(us8*)(&Als[ar * 40 + ag]) = a0;
    *(us8*)(&Bls[ar * 40 + ag]) = b0;
    __syncthreads();
    bf16x8 bf0 = *(const bf16x8*)(&Bls[(wn + lr) * 40 + lk8]);
    bf16x8 bf1 = *(const bf16x8*)(&Bls[(wn + 16 + lr) * 40 + lk8]);
#pragma unroll
    for (int fm = 0; fm < 2; fm++) {
      bf16x8 af = *(const bf16x8*)(&Als[(wm + fm * 16 + lr) * 40 + lk8]);
      acc[fm][0] = __builtin_amdgcn_mfma_f32_16x16x32_bf16(af, bf0, acc[fm][0], 0, 0, 0);
      acc[fm][1] = __builtin_amdgcn_mfma_f32_16x16x32_bf16(af, bf1, acc[fm][1], 0, 0, 0);
    }
  }
  const int r0 = (l >> 4) * 4;
#pragma unroll
  for (int fm = 0; fm < 2; fm++) {
    const size_t rowb = (size_t)(m0 + wm + fm * 16 + r0);
#pragma unroll
    for (int fn = 0; fn < 2; fn++) {
      const int col = wn + fn * 16 + lr;
#pragma unroll
      for (int r = 0; r < 4; r++)
        xdbl[(rowb + r) * XSTR + col] = acc[fm][fn][r];
    }
  }
}

// dt16[M][384] = bf16(softplus(x_dbl[:, :12] @ dt_proj_w^T + 2*dt_proj_b)).
__global__ __launch_bounds__(256) void dtproj_k(const float* __restrict__ xdbl,
                                                const float* __restrict__ dtwt,
                                                const float* __restrict__ dtb,
                                                unsigned short* __restrict__ dt16) {
  const int idx = blockIdx.x * 256 + threadIdx.x;
  const int q = (idx % 96) * 4;
  const size_t m = idx / 96;
  const float* xr = xdbl + m * XSTR;
  float xs[12];
  *(float4*)(xs) = *(const float4*)(xr);
  *(float4*)(xs + 4) = *(const float4*)(xr + 4);
  *(float4*)(xs + 8) = *(const float4*)(xr + 8);
  float4 bv = *(const float4*)(dtb + q);
  float4 s;
  s.x = 2.f * bv.x; s.y = 2.f * bv.y; s.z = 2.f * bv.z; s.w = 2.f * bv.w;
#pragma unroll
  for (int r = 0; r < DTRANK; r++) {
    float4 w4 = *(const float4*)(dtwt + r * DINNER + q);
    s.x = fmaf(xs[r], w4.x, s.x);
    s.y = fmaf(xs[r], w4.y, s.y);
    s.z = fmaf(xs[r], w4.z, s.z);
    s.w = fmaf(xs[r], w4.w, s.w);
  }
  ushort4 o;
  o.x = f2bf(fmaxf(s.x, 0.f) + __logf(1.f + __expf(-fabsf(s.x))));
  o.y = f2bf(fmaxf(s.y, 0.f) + __logf(1.f + __expf(-fabsf(s.y))));
  o.z = f2bf(fmaxf(s.z, 0.f) + __logf(1.f + __expf(-fabsf(s.z))));
  o.w = f2bf(fmaxf(s.w, 0.f) + __logf(1.f + __expf(-fabsf(s.w))));
  *(ushort4*)(dt16 + m * DINNER + q) = o;
}

// ---- chunked parallel scan, thread-per-(b,d), 16 states in registers ----
// CH=16 -> 2048 blocks = 8 blocks/CU: double the wave-level latency coverage.
__global__ __launch_bounds__(384, 6) void scan_part1(const unsigned short* __restrict__ dt16,
                                                     const unsigned short* __restrict__ u16,
                                                     const float* __restrict__ xdbl,
                                                     const float* __restrict__ A_log,
                                                     float* __restrict__ Dsum,
                                                     float* __restrict__ Sbuf) {
  __shared__ float Bs[CH][DSTATE];
  const int d = threadIdx.x;
  const int c = blockIdx.x, b = blockIdx.y;
  const size_t mbase = (size_t)b * SEQLEN + (size_t)c * CH;
  if (d < CH * 4) {
    const int r = d >> 2, q = d & 3;
    float4 v = *(const float4*)(xdbl + (mbase + r) * XSTR + DTRANK + q * 4);
    float* dst = &Bs[r][q * 4];
    dst[0] = v.x; dst[1] = v.y; dst[2] = v.z; dst[3] = v.w;
  }
  float Av[DSTATE];
#pragma unroll
  for (int q = 0; q < 4; q++) {
    float4 v = *(const float4*)(A_log + d * DSTATE + q * 4);
    Av[q * 4 + 0] = -__expf(v.x); Av[q * 4 + 1] = -__expf(v.y);
    Av[q * 4 + 2] = -__expf(v.z); Av[q * 4 + 3] = -__expf(v.w);
  }
  bool fastp = true;
#pragma unroll
  for (int n = 0; n < DSTATE; n++)
    fastp = fastp && (fabsf(Av[n] + (float)(n + 1)) < 1e-5f * (float)(n + 1));
  float dtsum = 0.f;
  __syncthreads();
  float dtv = bf2f(dt16[mbase * DINNER + d]);
  float uv  = bf2f(u16[mbase * DINNER + d]);
  float* Sp = Sbuf + ((size_t)(b * NC + c) * DINNER + d) * DSTATE;
  if (fastp) {
    f32x2 h2[8];
#pragma unroll
    for (int j = 0; j < 8; j++) h2[j] = (f32x2){0.f, 0.f};
    for (int l = 0; l < CH; l++) {
      const int lp = (l + 1 < CH) ? (l + 1) : l;
      const float dtn = bf2f(dt16[(mbase + lp) * DINNER + d]);
      const float un  = bf2f(u16[(mbase + lp) * DINNER + d]);
      const float du = dtv * uv;
      dtsum += dtv;
      const float e1 = __expf(-dtv);
      f32x2 av2[8];
      POW16P(av2, e1)
      const f32x2 du2 = (f32x2){du, du};
      const float* Lr = &Bs[l][0];
#pragma unroll
      for (int j = 0; j < 8; j++) {
        f32x2 b2 = *(const f32x2*)(Lr + 2 * j);
        h2[j] = pk_fma(av2[j], h2[j], pk_mul(du2, b2));
      }
      dtv = dtn; uv = un;
    }
#pragma unroll
    for (int q = 0; q < 4; q++) {
      float4 sv;
      sv.x = h2[2 * q].x; sv.y = h2[2 * q].y;
      sv.z = h2[2 * q + 1].x; sv.w = h2[2 * q + 1].y;
      *(float4*)(Sp + q * 4) = sv;
    }
  } else {
    float h[DSTATE];
#pragma unroll
    for (int n = 0; n < DSTATE; n++) h[n] = 0.f;
    for (int l = 0; l < CH; l++) {
      const int lp = (l + 1 < CH) ? (l + 1) : l;
      const float dtn = bf2f(dt16[(mbase + lp) * DINNER + d]);
      const float un  = bf2f(u16[(mbase + lp) * DINNER + d]);
      const float du = dtv * uv;
      dtsum += dtv;
#pragma unroll
      for (int n = 0; n < DSTATE; n++) {
        const float a = __expf(dtv * Av[n]);
        h[n] = fmaf(a, h[n], du * Bs[l][n]);
      }
      dtv = dtn; uv = un;
    }
#pragma unroll
    for (int q = 0; q < 4; q++) {
      float4 sv;
      sv.x = h[q * 4 + 0]; sv.y = h[q * 4 + 1]; sv.z = h[q * 4 + 2]; sv.w = h[q * 4 + 3];
      *(float4*)(Sp + q * 4) = sv;
    }
  }
  Dsum[(size_t)(b * NC + c) * DINNER + d] = dtsum;
}

// Pass 2: combine across chunks. P[n] reconstructed from dtsum via one exp.
__global__ __launch_bounds__(256) void scan_part2(const float* __restrict__ Dsum,
                                                  const float* __restrict__ Sbuf,
                                                  const float* __restrict__ A_log,
                                                  float* __restrict__ Hbuf) {
  const int i = blockIdx.x * 256 + threadIdx.x;    // b*(DINNER*DSTATE) + r
  const int b = i / (DINNER * DSTATE);
  const int r = i % (DINNER * DSTATE);             // d*16 + n
  const float Av = -__expf(A_log[r]);              // A_log flat index == r
  const size_t cs = DINNER * DSTATE;
  const size_t sbase = (size_t)b * NC * cs + r;
  const size_t dbase = (size_t)b * NC * DINNER + (r >> 4);
  float h = 0.f;
  for (int c0 = 0; c0 < NC; c0 += 8) {
    float dd[8], ss[8];
#pragma unroll
    for (int j = 0; j < 8; j++) {
      dd[j] = Dsum[dbase + (size_t)(c0 + j) * DINNER];
      ss[j] = Sbuf[sbase + (size_t)(c0 + j) * cs];
    }
    float pp[8];
#pragma unroll
    for (int j = 0; j < 8; j++) pp[j] = __expf(dd[j] * Av);
#pragma unroll
    for (int j = 0; j < 8; j++) {
      Hbuf[sbase + (size_t)(c0 + j) * cs] = h;
      h = fmaf(pp[j], h, ss[j]);
    }
  }
}

// Pass 3: re-run from h0; y = (h.C + D*u)*silu(z) emitted bf16 for out_proj.
__global__ __launch_bounds__(384, 6) void scan_part3(const unsigned short* __restrict__ dt16,
                                                     const unsigned short* __restrict__ u16,
                                                     const float* __restrict__ xdbl,
                                                     const float* __restrict__ A_log,
                                                     const float* __restrict__ Dsk,
                                                     const unsigned short* __restrict__ zb,
                                                     const float* __restrict__ H0,
                                                     unsigned short* __restrict__ yb) {
  __shared__ float BC[CH][2 * DSTATE];
  const int d = threadIdx.x;
  const int c = blockIdx.x, b = blockIdx.y;
  const size_t mbase = (size_t)b * SEQLEN + (size_t)c * CH;
  for (int i = d; i < CH * 8; i += 384) {
    const int r = i >> 3, q = i & 7;
    float4 v = *(const float4*)(xdbl + (mbase + r) * XSTR + DTRANK + q * 4);
    float* dst = &BC[r][q * 4];
    dst[0] = v.x; dst[1] = v.y; dst[2] = v.z; dst[3] = v.w;
  }
  float Av[DSTATE];
#pragma unroll
  for (int q = 0; q < 4; q++) {
    float4 v = *(const float4*)(A_log + d * DSTATE + q * 4);
    Av[q * 4 + 0] = -__expf(v.x); Av[q * 4 + 1] = -__expf(v.y);
    Av[q * 4 + 2] = -__expf(v.z); Av[q * 4 + 3] = -__expf(v.w);
  }
  bool fastp = true;
#pragma unroll
  for (int n = 0; n < DSTATE; n++)
    fastp = fastp && (fabsf(Av[n] + (float)(n + 1)) < 1e-5f * (float)(n + 1));
  const float Dv = Dsk[d];
  const float* Hp = H0 + ((size_t)(b * NC + c) * DINNER + d) * DSTATE;
  __syncthreads();
  float dtv = bf2f(dt16[mbase * DINNER + d]);
  float uv  = bf2f(u16[mbase * DINNER + d]);
  float zv  = bf2f(zb[mbase * DINNER + d]);
  if (fastp) {
    f32x2 h2[8];
#pragma unroll
    for (int q = 0; q < 4; q++) {
      float4 v = *(const float4*)(Hp + q * 4);
      h2[2 * q] = (f32x2){v.x, v.y};
      h2[2 * q + 1] = (f32x2){v.z, v.w};
    }
    for (int l = 0; l < CH; l++) {
      const int lp = (l + 1 < CH) ? (l + 1) : l;
      const float dtn = bf2f(dt16[(mbase + lp) * DINNER + d]);
      const float un  = bf2f(u16[(mbase + lp) * DINNER + d]);
      const float zn  = bf2f(zb[(mbase + lp) * DINNER + d]);
      const float du = dtv * uv;
      const float e1 = __expf(-dtv);
      f32x2 av2[8];
      POW16P(av2, e1)
      const f32x2 du2 = (f32x2){du, du};
      const float* Lr = &BC[l][0];
      f32x2 y2a = (f32x2){Dv * uv, 0.f};
      f32x2 y2b = (f32x2){0.f, 0.f};
#pragma unroll
      for (int j = 0; j < 8; j++) {
        f32x2 b2 = *(const f32x2*)(Lr + 2 * j);
        f32x2 c2 = *(const f32x2*)(Lr + DSTATE + 2 * j);
        h2[j] = pk_fma(av2[j], h2[j], pk_mul(du2, b2));
        if (j & 1) y2b = pk_fma(h2[j], c2, y2b);
        else       y2a = pk_fma(h2[j], c2, y2a);
      }
      const float yacc = (y2a.x + y2b.x) + (y2a.y + y2b.y);
      yb[(mbase + l) * DINNER + d] = f2bf(yacc * silu_f(zv));
      dtv = dtn; uv = un; zv = zn;
    }
  } else {
    float h[DSTATE];
#pragma unroll
    for (int q = 0; q < 4; q++) {
      float4 v = *(const float4*)(Hp + q * 4);
      h[q * 4 + 0] = v.x; h[q * 4 + 1] = v.y; h[q * 4 + 2] = v.z; h[q * 4 + 3] = v.w;
    }
    for (int l = 0; l < CH; l++) {
      const int lp = (l + 1 < CH) ? (l + 1) : l;
      const float dtn = bf2f(dt16[(mbase + lp) * DINNER + d]);
      const float un  = bf2f(u16[(mbase + lp) * DINNER + d]);
      const float zn  = bf2f(zb[(mbase + lp) * DINNER + d]);
      const float du = dtv * uv;
      float yacc = Dv * uv;
#pragma unroll
      for (int n = 0; n < DSTATE; n++) {
        const float a = __expf(dtv * Av[n]);
        h[n] = fmaf(a, h[n], du * BC[l][n]);
        yacc = fmaf(h[n], BC[l][DSTATE + n], yacc);
      }
      yb[(mbase + l) * DINNER + d] = f2bf(yacc * silu_f(zv));
      dtv = dtn; uv = un; zv = zn;
    }
  }
}

// out_proj: out[M][192] fp32 = yb[M][384] @ ow^T. BM=128 BN=64 BK=32, XCD swizzle.
__global__ __launch_bounds__(256) void gemm_out(const unsigned short* __restrict__ yb,
                                                const unsigned short* __restrict__ owb,
                                                float* __restrict__ out) {
  __shared__ unsigned short Als[128 * 40];
  __shared__ unsigned short Bls[64 * 40];
  const int tid = threadIdx.x;
  const int bid = blockIdx.y * 3 + blockIdx.x;        // 0..767
  const int lid = (bid & 7) * 96 + (bid >> 3);        // bijective (768%8==0)
  const int m0 = (lid / 3) * 128, n0 = (lid % 3) * 64;
  const int w = tid >> 6, l = tid & 63;
  const int wm = (w >> 1) * 64, wn = (w & 1) * 32;
  const int lr = l & 15, lk8 = (l >> 4) * 8;
  const int ar = tid >> 1, ag = (tid & 1) * 16;
  const int br = tid >> 2, bg = (tid & 3) * 8;
  const unsigned short* Ap = yb + (size_t)(m0 + ar) * DINNER + ag;
  const unsigned short* Wp = owb + (size_t)(n0 + br) * DINNER + bg;
  f32x4 acc[4][2];
#pragma unroll
  for (int i = 0; i < 4; i++)
#pragma unroll
    for (int j = 0; j < 2; j++) acc[i][j] = (f32x4){0.f, 0.f, 0.f, 0.f};
#pragma unroll
  for (int k0 = 0; k0 < DINNER; k0 += 32) {
    us8 a0 = *(const us8*)(Ap + k0);
    us8 a1 = *(const us8*)(Ap + k0 + 8);
    us8 bv = *(const us8*)(Wp + k0);
    __syncthreads();
    *(us8*)(&Als[ar * 40 + ag]) = a0;
    *(us8*)(&Als[ar * 40 + ag + 8]) = a1;
    *(us8*)(&Bls[br * 40 + bg]) = bv;
    __syncthreads();
    bf16x8 b0 = *(const bf16x8*)(&Bls[(wn + lr) * 40 + lk8]);
    bf16x8 b1 = *(const bf16x8*)(&Bls[(wn + 16 + lr) * 40 + lk8]);
#pragma unroll
    for (int fm = 0; fm < 4; fm++) {
      bf16x8 af = *(const bf16x8*)(&Als[(wm + fm * 16 + lr) * 40 + lk8]);
      acc[fm][0] = __builtin_amdgcn_mfma_f32_16x16x32_bf16(af, b0, acc[fm][0], 0, 0, 0);
      acc[fm][1] = __builtin_amdgcn_mfma_f32_16x16x32_bf16(af, b1, acc[fm][1], 0, 0, 0);
    }
  }
  const int r0 = (l >> 4) * 4;
#pragma unroll
  for (int fm = 0; fm < 4; fm++) {
    const size_t rowb = (size_t)(m0 + wm + fm * 16 + r0);
#pragma unroll
    for (int fn = 0; fn < 2; fn++) {
      const int col = n0 + wn + fn * 16 + lr;
#pragma unroll
      for (int r = 0; r < 4; r++)
        out[(rowb + r) * DMODEL + col] = acc[fm][fn][r];
    }
  }
}

extern "C" void kernel_launch(void* const* d_in, const int* in_sizes, int n_in,
                              void* d_out, int out_size, void* d_ws, size_t ws_size,
                              hipStream_t stream) {
  const float* hs   = (const float*)d_in[0];
  const float* in_w = (const float*)d_in[1];
  const float* cw   = (const float*)d_in[2];
  const float* cb   = (const float*)d_in[3];
  const float* xw   = (const float*)d_in[4];
  const float* dtw  = (const float*)d_in[5];
  const float* dtb  = (const float*)d_in[6];
  const float* alog = (const float*)d_in[7];
  const float* dsk  = (const float*)d_in[8];
  const float* ow   = (const float*)d_in[9];
  float* out = (float*)d_out;

  // ws layout (bytes), total ~213 MB
  char* ws = (char*)d_ws;
  unsigned short* xb   = (unsigned short*)(ws);                // [M][384] bf16 25.17 MB (yb after conv)
  unsigned short* u16  = (unsigned short*)(ws + 25165824);     // [M][384] bf16 25.17 MB
  float* xdbl = (float*)(ws + 50331648);                       // [M][64]  fp32  8.39 MB
  unsigned short* dt16 = (unsigned short*)(ws + 58720256);     // [M][384] bf16 25.17 MB
  float* Hbuf = (float*)(ws + 83886080);                       // [B][256][D][N] 50.33 MB (h0)
  float* Sbuf = (float*)(ws + 134217728);                      // 50.33 MB
  unsigned short* zb  = (unsigned short*)(ws + 184549376);     // [M][384] bf16 25.17 MB
  unsigned short* wb  = (unsigned short*)(ws + 209715200);     // [768][192] bf16 294912 B
  unsigned short* wxb = (unsigned short*)(ws + 210010112);     // [64][384]  bf16  49152 B
  unsigned short* owb = (unsigned short*)(ws + 210059264);     // [192][384] bf16 147456 B
  float* dtwt = (float*)(ws + 210206720);                      // [12][384]  fp32  18432 B
  float* Dsum = (float*)(ws + 210225152);                      // [B][256][384] fp32 3.15 MB
  unsigned short* yb  = xb;   // part3 output over dead xb

  // 0. weight casts/pads + dtw transpose (one kernel)
  prep_k<<<576, 256, 0, stream>>>(in_w, xw, ow, dtw, wb, wxb, owb, dtwt);
  // 1. in_proj (bf16 MFMA, XCD-swizzled, bf16 x|z outputs)
  gemm_in<<<dim3(6, 256), 256, 0, stream>>>(hs, wb, xb, zb);
  // 2. depthwise conv + SiLU (bf16 -> bf16)
  conv_silu_k<<<(MTOT * 48) / 256, 256, 0, stream>>>(xb, cw, cb, u16);
  // 3. x_proj (bf16 MFMA, fp32 out)
  xproj_mfma<<<MTOT / 64, 256, 0, stream>>>(u16, wxb, xdbl);
  // 4. dt_proj + fast softplus -> bf16 (double bias per reference)
  dtproj_k<<<(MTOT * 96) / 256, 256, 0, stream>>>(xdbl, dtwt, dtb, dt16);
  // 5. chunked selective scan (CH=16 -> 2048 blocks = 8 blocks/CU)
  scan_part1<<<dim3(NC, BATCH), 384, 0, stream>>>(dt16, u16, xdbl, alog, Dsum, Sbuf);
  scan_part2<<<(BATCH * DINNER * DSTATE) / 256, 256, 0, stream>>>(Dsum, Sbuf, alog, Hbuf);
  scan_part3<<<dim3(NC, BATCH), 384, 0, stream>>>(dt16, u16, xdbl, alog, dsk, zb, Hbuf, yb);
  // 6. out_proj (bf16 MFMA, XCD-swizzled)
  gemm_out<<<dim3(3, 256), 256, 0, stream>>>(yb, owb, out);
}

// Round 17
// 173.857 us; speedup vs baseline: 1.2123x; 1.2123x over previous
//
#include <hip/hip_runtime.h>
#include <cmath>

#define BATCH 8
#define SEQLEN 4096
#define DMODEL 192
#define DINNER 384
#define DSTATE 16
#define DTRANK 12
#define XSTR 64            // padded x_dbl row stride (44 real cols)
#define MTOT (BATCH*SEQLEN)
#define CH 32              // scan chunk length
#define NC (SEQLEN/CH)     // 128 chunks

typedef __bf16 bf16x8 __attribute__((ext_vector_type(8)));
typedef float f32x4 __attribute__((ext_vector_type(4)));
typedef float f32x2 __attribute__((ext_vector_type(2)));
typedef unsigned short us8 __attribute__((ext_vector_type(8)));

__device__ __forceinline__ float silu_f(float x) { return x / (1.f + __expf(-x)); }
__device__ __forceinline__ unsigned short f2bf(float f) {
  unsigned u = __float_as_uint(f);
  return (unsigned short)((u + 0x7FFF + ((u >> 16) & 1)) >> 16);   // RNE
}
__device__ __forceinline__ float bf2f(unsigned short b) {
  return __uint_as_float(((unsigned)b) << 16);
}

// packed fp32 (VOP3P)
__device__ __forceinline__ f32x2 pk_mul(f32x2 a, f32x2 b) {
  f32x2 d; asm("v_pk_mul_f32 %0, %1, %2" : "=v"(d) : "v"(a), "v"(b)); return d;
}
__device__ __forceinline__ f32x2 pk_fma(f32x2 a, f32x2 b, f32x2 c) {
  f32x2 d; asm("v_pk_fma_f32 %0, %1, %2, %3" : "=v"(d) : "v"(a), "v"(b), "v"(c)); return d;
}

// av2[j] = {e1^(2j+1), e1^(2j+2)}; 1 scalar mul + 7 pk_mul
#define POW16P(av2, e1)                                                     \
  { const float e2s_ = (e1) * (e1);                                         \
    av2[0] = (f32x2){(e1), e2s_};                                           \
    const f32x2 e2b_ = (f32x2){e2s_, e2s_};                                 \
    av2[1] = pk_mul(av2[0], e2b_);                                          \
    const float e4_ = av2[1].y;                                             \
    const f32x2 e4b_ = (f32x2){e4_, e4_};                                   \
    av2[2] = pk_mul(av2[0], e4b_);                                          \
    av2[3] = pk_mul(av2[1], e4b_);                                          \
    const float e8_ = av2[3].y;                                             \
    const f32x2 e8b_ = (f32x2){e8_, e8_};                                   \
    av2[4] = pk_mul(av2[0], e8b_);                                          \
    av2[5] = pk_mul(av2[1], e8b_);                                          \
    av2[6] = pk_mul(av2[2], e8b_);                                          \
    av2[7] = pk_mul(av2[3], e8b_); }

// prep: cast in_proj_w, pad+cast x_proj_w, cast out_proj_w, TRANSPOSE dt_proj_w
__global__ __launch_bounds__(256) void prep_k(const float* __restrict__ in_w,
                                              const float* __restrict__ xw,
                                              const float* __restrict__ ow,
                                              const float* __restrict__ dtw,
                                              unsigned short* __restrict__ wb,
                                              unsigned short* __restrict__ wxb,
                                              unsigned short* __restrict__ owb,
                                              float* __restrict__ dtwt) {
  const int i = blockIdx.x * 256 + threadIdx.x;
  if (i < 768 * DMODEL) wb[i] = f2bf(in_w[i]);
  if (i < XSTR * DINNER) wxb[i] = (i < 44 * DINNER) ? f2bf(xw[i]) : (unsigned short)0;
  if (i < DMODEL * DINNER) owb[i] = f2bf(ow[i]);
  if (i < DTRANK * DINNER) dtwt[i] = dtw[(i % DINNER) * DTRANK + (i / DINNER)];
}

// in_proj: [M][768] = hs[M][192] @ in_w^T. BM=128 BN=128 BK=32, XCD-chunked swizzle.
__global__ __launch_bounds__(256) void gemm_in(const float* __restrict__ hs,
                                               const unsigned short* __restrict__ wb,
                                               unsigned short* __restrict__ xb,
                                               unsigned short* __restrict__ zb) {
  __shared__ unsigned short Als[128 * 40];   // 80B rows
  __shared__ unsigned short Bls[128 * 40];
  const int tid = threadIdx.x;
  const int bid = blockIdx.y * 6 + blockIdx.x;        // 0..1535
  const int lid = (bid & 7) * 192 + (bid >> 3);       // bijective (1536%8==0)
  const int m0 = (lid / 6) * 128, n0 = (lid % 6) * 128;
  const int w = tid >> 6, l = tid & 63;
  const int wm = (w >> 1) * 64, wn = (w & 1) * 64;
  const int lr = l & 15, lk8 = (l >> 4) * 8;
  const int ar = tid >> 1, ag = (tid & 1) * 16;
  const float* Ap = hs + (size_t)(m0 + ar) * DMODEL + ag;
  const unsigned short* Wp = wb + (size_t)(n0 + ar) * DMODEL + ag;
  f32x4 acc[4][4];
#pragma unroll
  for (int i = 0; i < 4; i++)
#pragma unroll
    for (int j = 0; j < 4; j++) acc[i][j] = (f32x4){0.f, 0.f, 0.f, 0.f};
#pragma unroll
  for (int k0 = 0; k0 < DMODEL; k0 += 32) {
    float4 f0 = *(const float4*)(Ap + k0);
    float4 f1 = *(const float4*)(Ap + k0 + 4);
    float4 f2 = *(const float4*)(Ap + k0 + 8);
    float4 f3 = *(const float4*)(Ap + k0 + 12);
    us8 b0 = *(const us8*)(Wp + k0);
    us8 b1 = *(const us8*)(Wp + k0 + 8);
    us8 a0, a1;
    a0[0] = f2bf(f0.x); a0[1] = f2bf(f0.y); a0[2] = f2bf(f0.z); a0[3] = f2bf(f0.w);
    a0[4] = f2bf(f1.x); a0[5] = f2bf(f1.y); a0[6] = f2bf(f1.z); a0[7] = f2bf(f1.w);
    a1[0] = f2bf(f2.x); a1[1] = f2bf(f2.y); a1[2] = f2bf(f2.z); a1[3] = f2bf(f2.w);
    a1[4] = f2bf(f3.x); a1[5] = f2bf(f3.y); a1[6] = f2bf(f3.z); a1[7] = f2bf(f3.w);
    __syncthreads();
    *(us8*)(&Als[ar * 40 + ag]) = a0;
    *(us8*)(&Als[ar * 40 + ag + 8]) = a1;
    *(us8*)(&Bls[ar * 40 + ag]) = b0;
    *(us8*)(&Bls[ar * 40 + ag + 8]) = b1;
    __syncthreads();
    bf16x8 bfr[4];
#pragma unroll
    for (int fn = 0; fn < 4; fn++)
      bfr[fn] = *(const bf16x8*)(&Bls[(wn + fn * 16 + lr) * 40 + lk8]);
#pragma unroll
    for (int fm = 0; fm < 4; fm++) {
      bf16x8 af = *(const bf16x8*)(&Als[(wm + fm * 16 + lr) * 40 + lk8]);
#pragma unroll
      for (int fn = 0; fn < 4; fn++)
        acc[fm][fn] = __builtin_amdgcn_mfma_f32_16x16x32_bf16(af, bfr[fn], acc[fm][fn], 0, 0, 0);
    }
  }
  const int r0 = (l >> 4) * 4;   // C/D: col=lane&15, row=(lane>>4)*4+reg
  unsigned short* dst = (n0 < DINNER) ? xb : zb;
  const int cb0 = (n0 < DINNER) ? n0 : (n0 - DINNER);
#pragma unroll
  for (int fm = 0; fm < 4; fm++) {
    const size_t rowb = (size_t)(m0 + wm + fm * 16 + r0);
#pragma unroll
    for (int fn = 0; fn < 4; fn++) {
      const int col = cb0 + wn + fn * 16 + lr;
#pragma unroll
      for (int r = 0; r < 4; r++)
        dst[(rowb + r) * DINNER + col] = f2bf(acc[fm][fn][r]);
    }
  }
}

// depthwise conv (k=3, same-pad) + SiLU, bf16 in/out, 8 channels/thread
__global__ __launch_bounds__(256) void conv_silu_k(const unsigned short* __restrict__ xb,
                                                   const float* __restrict__ cw,
                                                   const float* __restrict__ cb,
                                                   unsigned short* __restrict__ u16) {
  __shared__ float cws[DINNER * 4];   // [0..3*384) = cw, [3*384..) = cb
  const int tid = threadIdx.x;
  for (int i = tid; i < DINNER * 4; i += 256)
    cws[i] = (i < DINNER * 3) ? cw[i] : cb[i - DINNER * 3];
  __syncthreads();
  const int idx = blockIdx.x * 256 + tid;
  const int d = (idx % 48) * 8;
  const int m = idx / 48;
  const int l = m % SEQLEN;
  const us8 c0 = *(const us8*)(xb + (size_t)m * DINNER + d);
  const bool hm = (l > 0), hp = (l < SEQLEN - 1);
  us8 cm = c0, cp = c0;
  if (hm) cm = *(const us8*)(xb + (size_t)(m - 1) * DINNER + d);
  if (hp) cp = *(const us8*)(xb + (size_t)(m + 1) * DINNER + d);
  us8 o;
#pragma unroll
  for (int j = 0; j < 8; j++) {
    const int dj = d + j;
    float s = cws[DINNER * 3 + dj] + cws[dj * 3 + 1] * bf2f(c0[j]);
    if (hm) s += cws[dj * 3 + 0] * bf2f(cm[j]);
    if (hp) s += cws[dj * 3 + 2] * bf2f(cp[j]);
    o[j] = f2bf(silu_f(s));
  }
  *(us8*)(u16 + (size_t)m * DINNER + d) = o;
}

// x_proj (bf16 MFMA) with FUSED dt_proj epilogue: each block owns 64 full
// rows of xdbl, so the 12 dt-columns are block-local. dt16 is emitted here
// with the identical fmaf ordering as the standalone kernel (bit-identical).
__global__ __launch_bounds__(256) void xproj_dt(const unsigned short* __restrict__ u16,
                                                const unsigned short* __restrict__ wxb,
                                                const float* __restrict__ dtwt,
                                                const float* __restrict__ dtb,
                                                float* __restrict__ xdbl,
                                                unsigned short* __restrict__ dt16) {
  __shared__ unsigned short Als[64 * 40];
  __shared__ unsigned short Bls[64 * 40];
  __shared__ float XT[64 * 16];            // dt-columns 0..15 of this tile
  __shared__ float WDt[DTRANK * DINNER];   // 18 KB transposed dt weights
  __shared__ float BDt[DINNER];
  const int tid = threadIdx.x;
  const int m0 = blockIdx.x * 64;
  for (int i = tid; i < DTRANK * DINNER; i += 256) WDt[i] = dtwt[i];
  for (int i = tid; i < DINNER; i += 256) BDt[i] = dtb[i];
  const int w = tid >> 6, l = tid & 63;
  const int wm = (w >> 1) * 32, wn = (w & 1) * 32;
  const int lr = l & 15, lk8 = (l >> 4) * 8;
  const int ar = tid >> 2, ag = (tid & 3) * 8;
  const unsigned short* Ap = u16 + (size_t)(m0 + ar) * DINNER + ag;
  const unsigned short* Wp = wxb + (size_t)ar * DINNER + ag;
  f32x4 acc[2][2];
#pragma unroll
  for (int i = 0; i < 2; i++)
#pragma unroll
    for (int j = 0; j < 2; j++) acc[i][j] = (f32x4){0.f, 0.f, 0.f, 0.f};
#pragma unroll
  for (int k0 = 0; k0 < DINNER; k0 += 32) {
    us8 a0 = *(const us8*)(Ap + k0);
    us8 b0 = *(const us8*)(Wp + k0);
    __syncthreads();
    *(us8*)(&Als[ar * 40 + ag]) = a0;
    *(us8*)(&Bls[ar * 40 + ag]) = b0;
    __syncthreads();
    bf16x8 bf0 = *(const bf16x8*)(&Bls[(wn + lr) * 40 + lk8]);
    bf16x8 bf1 = *(const bf16x8*)(&Bls[(wn + 16 + lr) * 40 + lk8]);
#pragma unroll
    for (int fm = 0; fm < 2; fm++) {
      bf16x8 af = *(const bf16x8*)(&Als[(wm + fm * 16 + lr) * 40 + lk8]);
      acc[fm][0] = __builtin_amdgcn_mfma_f32_16x16x32_bf16(af, bf0, acc[fm][0], 0, 0, 0);
      acc[fm][1] = __builtin_amdgcn_mfma_f32_16x16x32_bf16(af, bf1, acc[fm][1], 0, 0, 0);
    }
  }
  const int r0 = (l >> 4) * 4;
#pragma unroll
  for (int fm = 0; fm < 2; fm++) {
    const size_t rowb = (size_t)(m0 + wm + fm * 16 + r0);
    const int lrow = wm + fm * 16 + r0;
#pragma unroll
    for (int fn = 0; fn < 2; fn++) {
      const int col = wn + fn * 16 + lr;
#pragma unroll
      for (int r = 0; r < 4; r++)
        xdbl[(rowb + r) * XSTR + col] = acc[fm][fn][r];
    }
    if (wn == 0) {   // stage cols 0..15 for the dt epilogue
#pragma unroll
      for (int r = 0; r < 4; r++)
        XT[(lrow + r) * 16 + lr] = acc[fm][0][r];
    }
  }
  __syncthreads();
  // dt epilogue: 64 rows x 384 d, identical math to standalone dtproj
  for (int i = tid; i < 64 * 96; i += 256) {
    const int row = i / 96, q = (i % 96) * 4;
    const float* xs = &XT[row * 16];
    float4 bv = *(const float4*)(BDt + q);
    float4 s;
    s.x = 2.f * bv.x; s.y = 2.f * bv.y; s.z = 2.f * bv.z; s.w = 2.f * bv.w;
#pragma unroll
    for (int r = 0; r < DTRANK; r++) {
      float4 w4 = *(const float4*)(WDt + r * DINNER + q);
      s.x = fmaf(xs[r], w4.x, s.x);
      s.y = fmaf(xs[r], w4.y, s.y);
      s.z = fmaf(xs[r], w4.z, s.z);
      s.w = fmaf(xs[r], w4.w, s.w);
    }
    ushort4 o;
    o.x = f2bf(fmaxf(s.x, 0.f) + __logf(1.f + __expf(-fabsf(s.x))));
    o.y = f2bf(fmaxf(s.y, 0.f) + __logf(1.f + __expf(-fabsf(s.y))));
    o.z = f2bf(fmaxf(s.z, 0.f) + __logf(1.f + __expf(-fabsf(s.z))));
    o.w = f2bf(fmaxf(s.w, 0.f) + __logf(1.f + __expf(-fabsf(s.w))));
    *(ushort4*)(dt16 + (size_t)(m0 + row) * DINNER + q) = o;
  }
}

// ---- chunked parallel scan, thread-per-(b,d), 16 states in registers ----
__global__ __launch_bounds__(384, 6) void scan_part1(const unsigned short* __restrict__ dt16,
                                                     const unsigned short* __restrict__ u16,
                                                     const float* __restrict__ xdbl,
                                                     const float* __restrict__ A_log,
                                                     float* __restrict__ Dsum,
                                                     float* __restrict__ Sbuf) {
  __shared__ float Bs[CH][DSTATE];
  const int d = threadIdx.x;
  const int c = blockIdx.x, b = blockIdx.y;
  const size_t mbase = (size_t)b * SEQLEN + (size_t)c * CH;
  if (d < CH * 4) {
    const int r = d >> 2, q = d & 3;
    float4 v = *(const float4*)(xdbl + (mbase + r) * XSTR + DTRANK + q * 4);
    float* dst = &Bs[r][q * 4];
    dst[0] = v.x; dst[1] = v.y; dst[2] = v.z; dst[3] = v.w;
  }
  float Av[DSTATE];
#pragma unroll
  for (int q = 0; q < 4; q++) {
    float4 v = *(const float4*)(A_log + d * DSTATE + q * 4);
    Av[q * 4 + 0] = -__expf(v.x); Av[q * 4 + 1] = -__expf(v.y);
    Av[q * 4 + 2] = -__expf(v.z); Av[q * 4 + 3] = -__expf(v.w);
  }
  bool fastp = true;
#pragma unroll
  for (int n = 0; n < DSTATE; n++)
    fastp = fastp && (fabsf(Av[n] + (float)(n + 1)) < 1e-5f * (float)(n + 1));
  float dtsum = 0.f;
  __syncthreads();
  float dtv = bf2f(dt16[mbase * DINNER + d]);
  float uv  = bf2f(u16[mbase * DINNER + d]);
  float* Sp = Sbuf + ((size_t)(b * NC + c) * DINNER + d) * DSTATE;
  if (fastp) {
    f32x2 h2[8];
#pragma unroll
    for (int j = 0; j < 8; j++) h2[j] = (f32x2){0.f, 0.f};
    for (int l = 0; l < CH; l++) {
      const int lp = (l + 1 < CH) ? (l + 1) : l;
      const float dtn = bf2f(dt16[(mbase + lp) * DINNER + d]);
      const float un  = bf2f(u16[(mbase + lp) * DINNER + d]);
      const float du = dtv * uv;
      dtsum += dtv;
      const float e1 = __expf(-dtv);
      f32x2 av2[8];
      POW16P(av2, e1)
      const f32x2 du2 = (f32x2){du, du};
      const float* Lr = &Bs[l][0];
#pragma unroll
      for (int j = 0; j < 8; j++) {
        f32x2 b2 = *(const f32x2*)(Lr + 2 * j);
        h2[j] = pk_fma(av2[j], h2[j], pk_mul(du2, b2));
      }
      dtv = dtn; uv = un;
    }
#pragma unroll
    for (int q = 0; q < 4; q++) {
      float4 sv;
      sv.x = h2[2 * q].x; sv.y = h2[2 * q].y;
      sv.z = h2[2 * q + 1].x; sv.w = h2[2 * q + 1].y;
      *(float4*)(Sp + q * 4) = sv;
    }
  } else {
    float h[DSTATE];
#pragma unroll
    for (int n = 0; n < DSTATE; n++) h[n] = 0.f;
    for (int l = 0; l < CH; l++) {
      const int lp = (l + 1 < CH) ? (l + 1) : l;
      const float dtn = bf2f(dt16[(mbase + lp) * DINNER + d]);
      const float un  = bf2f(u16[(mbase + lp) * DINNER + d]);
      const float du = dtv * uv;
      dtsum += dtv;
#pragma unroll
      for (int n = 0; n < DSTATE; n++) {
        const float a = __expf(dtv * Av[n]);
        h[n] = fmaf(a, h[n], du * Bs[l][n]);
      }
      dtv = dtn; uv = un;
    }
#pragma unroll
    for (int q = 0; q < 4; q++) {
      float4 sv;
      sv.x = h[q * 4 + 0]; sv.y = h[q * 4 + 1]; sv.z = h[q * 4 + 2]; sv.w = h[q * 4 + 3];
      *(float4*)(Sp + q * 4) = sv;
    }
  }
  Dsum[(size_t)(b * NC + c) * DINNER + d] = dtsum;
}

// Pass 2: combine across chunks. P[n] reconstructed from dtsum via one exp.
__global__ __launch_bounds__(256) void scan_part2(const float* __restrict__ Dsum,
                                                  const float* __restrict__ Sbuf,
                                                  const float* __restrict__ A_log,
                                                  float* __restrict__ Hbuf) {
  const int i = blockIdx.x * 256 + threadIdx.x;    // b*(DINNER*DSTATE) + r
  const int b = i / (DINNER * DSTATE);
  const int r = i % (DINNER * DSTATE);             // d*16 + n
  const float Av = -__expf(A_log[r]);              // A_log flat index == r
  const size_t cs = DINNER * DSTATE;
  const size_t sbase = (size_t)b * NC * cs + r;
  const size_t dbase = (size_t)b * NC * DINNER + (r >> 4);
  float h = 0.f;
  for (int c0 = 0; c0 < NC; c0 += 8) {
    float dd[8], ss[8];
#pragma unroll
    for (int j = 0; j < 8; j++) {
      dd[j] = Dsum[dbase + (size_t)(c0 + j) * DINNER];
      ss[j] = Sbuf[sbase + (size_t)(c0 + j) * cs];
    }
    float pp[8];
#pragma unroll
    for (int j = 0; j < 8; j++) pp[j] = __expf(dd[j] * Av);
#pragma unroll
    for (int j = 0; j < 8; j++) {
      Hbuf[sbase + (size_t)(c0 + j) * cs] = h;
      h = fmaf(pp[j], h, ss[j]);
    }
  }
}

// Pass 3: re-run from h0; y = (h.C + D*u)*silu(z) emitted bf16 for out_proj.
__global__ __launch_bounds__(384, 6) void scan_part3(const unsigned short* __restrict__ dt16,
                                                     const unsigned short* __restrict__ u16,
                                                     const float* __restrict__ xdbl,
                                                     const float* __restrict__ A_log,
                                                     const float* __restrict__ Dsk,
                                                     const unsigned short* __restrict__ zb,
                                                     const float* __restrict__ H0,
                                                     unsigned short* __restrict__ yb) {
  __shared__ float BC[CH][2 * DSTATE];
  const int d = threadIdx.x;
  const int c = blockIdx.x, b = blockIdx.y;
  const size_t mbase = (size_t)b * SEQLEN + (size_t)c * CH;
  for (int i = d; i < CH * 8; i += 384) {
    const int r = i >> 3, q = i & 7;
    float4 v = *(const float4*)(xdbl + (mbase + r) * XSTR + DTRANK + q * 4);
    float* dst = &BC[r][q * 4];
    dst[0] = v.x; dst[1] = v.y; dst[2] = v.z; dst[3] = v.w;
  }
  float Av[DSTATE];
#pragma unroll
  for (int q = 0; q < 4; q++) {
    float4 v = *(const float4*)(A_log + d * DSTATE + q * 4);
    Av[q * 4 + 0] = -__expf(v.x); Av[q * 4 + 1] = -__expf(v.y);
    Av[q * 4 + 2] = -__expf(v.z); Av[q * 4 + 3] = -__expf(v.w);
  }
  bool fastp = true;
#pragma unroll
  for (int n = 0; n < DSTATE; n++)
    fastp = fastp && (fabsf(Av[n] + (float)(n + 1)) < 1e-5f * (float)(n + 1));
  const float Dv = Dsk[d];
  const float* Hp = H0 + ((size_t)(b * NC + c) * DINNER + d) * DSTATE;
  __syncthreads();
  float dtv = bf2f(dt16[mbase * DINNER + d]);
  float uv  = bf2f(u16[mbase * DINNER + d]);
  float zv  = bf2f(zb[mbase * DINNER + d]);
  if (fastp) {
    f32x2 h2[8];
#pragma unroll
    for (int q = 0; q < 4; q++) {
      float4 v = *(const float4*)(Hp + q * 4);
      h2[2 * q] = (f32x2){v.x, v.y};
      h2[2 * q + 1] = (f32x2){v.z, v.w};
    }
    for (int l = 0; l < CH; l++) {
      const int lp = (l + 1 < CH) ? (l + 1) : l;
      const float dtn = bf2f(dt16[(mbase + lp) * DINNER + d]);
      const float un  = bf2f(u16[(mbase + lp) * DINNER + d]);
      const float zn  = bf2f(zb[(mbase + lp) * DINNER + d]);
      const float du = dtv * uv;
      const float e1 = __expf(-dtv);
      f32x2 av2[8];
      POW16P(av2, e1)
      const f32x2 du2 = (f32x2){du, du};
      const float* Lr = &BC[l][0];
      f32x2 y2a = (f32x2){Dv * uv, 0.f};
      f32x2 y2b = (f32x2){0.f, 0.f};
#pragma unroll
      for (int j = 0; j < 8; j++) {
        f32x2 b2 = *(const f32x2*)(Lr + 2 * j);
        f32x2 c2 = *(const f32x2*)(Lr + DSTATE + 2 * j);
        h2[j] = pk_fma(av2[j], h2[j], pk_mul(du2, b2));
        if (j & 1) y2b = pk_fma(h2[j], c2, y2b);
        else       y2a = pk_fma(h2[j], c2, y2a);
      }
      const float yacc = (y2a.x + y2b.x) + (y2a.y + y2b.y);
      yb[(mbase + l) * DINNER + d] = f2bf(yacc * silu_f(zv));
      dtv = dtn; uv = un; zv = zn;
    }
  } else {
    float h[DSTATE];
#pragma unroll
    for (int q = 0; q < 4; q++) {
      float4 v = *(const float4*)(Hp + q * 4);
      h[q * 4 + 0] = v.x; h[q * 4 + 1] = v.y; h[q * 4 + 2] = v.z; h[q * 4 + 3] = v.w;
    }
    for (int l = 0; l < CH; l++) {
      const int lp = (l + 1 < CH) ? (l + 1) : l;
      const float dtn = bf2f(dt16[(mbase + lp) * DINNER + d]);
      const float un  = bf2f(u16[(mbase + lp) * DINNER + d]);
      const float zn  = bf2f(zb[(mbase + lp) * DINNER + d]);
      const float du = dtv * uv;
      float yacc = Dv * uv;
#pragma unroll
      for (int n = 0; n < DSTATE; n++) {
        const float a = __expf(dtv * Av[n]);
        h[n] = fmaf(a, h[n], du * BC[l][n]);
        yacc = fmaf(h[n], BC[l][DSTATE + n], yacc);
      }
      yb[(mbase + l) * DINNER + d] = f2bf(yacc * silu_f(zv));
      dtv = dtn; uv = un; zv = zn;
    }
  }
}

// out_proj: out[M][192] fp32 = yb[M][384] @ ow^T. BM=128 BN=64 BK=32, XCD swizzle.
__global__ __launch_bounds__(256) void gemm_out(const unsigned short* __restrict__ yb,
                                                const unsigned short* __restrict__ owb,
                                                float* __restrict__ out) {
  __shared__ unsigned short Als[128 * 40];
  __shared__ unsigned short Bls[64 * 40];
  const int tid = threadIdx.x;
  const int bid = blockIdx.y * 3 + blockIdx.x;        // 0..767
  const int lid = (bid & 7) * 96 + (bid >> 3);        // bijective (768%8==0)
  const int m0 = (lid / 3) * 128, n0 = (lid % 3) * 64;
  const int w = tid >> 6, l = tid & 63;
  const int wm = (w >> 1) * 64, wn = (w & 1) * 32;
  const int lr = l & 15, lk8 = (l >> 4) * 8;
  const int ar = tid >> 1, ag = (tid & 1) * 16;
  const int br = tid >> 2, bg = (tid & 3) * 8;
  const unsigned short* Ap = yb + (size_t)(m0 + ar) * DINNER + ag;
  const unsigned short* Wp = owb + (size_t)(n0 + br) * DINNER + bg;
  f32x4 acc[4][2];
#pragma unroll
  for (int i = 0; i < 4; i++)
#pragma unroll
    for (int j = 0; j < 2; j++) acc[i][j] = (f32x4){0.f, 0.f, 0.f, 0.f};
#pragma unroll
  for (int k0 = 0; k0 < DINNER; k0 += 32) {
    us8 a0 = *(const us8*)(Ap + k0);
    us8 a1 = *(const us8*)(Ap + k0 + 8);
    us8 bv = *(const us8*)(Wp + k0);
    __syncthreads();
    *(us8*)(&Als[ar * 40 + ag]) = a0;
    *(us8*)(&Als[ar * 40 + ag + 8]) = a1;
    *(us8*)(&Bls[br * 40 + bg]) = bv;
    __syncthreads();
    bf16x8 b0 = *(const bf16x8*)(&Bls[(wn + lr) * 40 + lk8]);
    bf16x8 b1 = *(const bf16x8*)(&Bls[(wn + 16 + lr) * 40 + lk8]);
#pragma unroll
    for (int fm = 0; fm < 4; fm++) {
      bf16x8 af = *(const bf16x8*)(&Als[(wm + fm * 16 + lr) * 40 + lk8]);
      acc[fm][0] = __builtin_amdgcn_mfma_f32_16x16x32_bf16(af, b0, acc[fm][0], 0, 0, 0);
      acc[fm][1] = __builtin_amdgcn_mfma_f32_16x16x32_bf16(af, b1, acc[fm][1], 0, 0, 0);
    }
  }
  const int r0 = (l >> 4) * 4;
#pragma unroll
  for (int fm = 0; fm < 4; fm++) {
    const size_t rowb = (size_t)(m0 + wm + fm * 16 + r0);
#pragma unroll
    for (int fn = 0; fn < 2; fn++) {
      const int col = n0 + wn + fn * 16 + lr;
#pragma unroll
      for (int r = 0; r < 4; r++)
        out[(rowb + r) * DMODEL + col] = acc[fm][fn][r];
    }
  }
}

extern "C" void kernel_launch(void* const* d_in, const int* in_sizes, int n_in,
                              void* d_out, int out_size, void* d_ws, size_t ws_size,
                              hipStream_t stream) {
  const float* hs   = (const float*)d_in[0];
  const float* in_w = (const float*)d_in[1];
  const float* cw   = (const float*)d_in[2];
  const float* cb   = (const float*)d_in[3];
  const float* xw   = (const float*)d_in[4];
  const float* dtw  = (const float*)d_in[5];
  const float* dtb  = (const float*)d_in[6];
  const float* alog = (const float*)d_in[7];
  const float* dsk  = (const float*)d_in[8];
  const float* ow   = (const float*)d_in[9];
  float* out = (float*)d_out;

  // ws layout (bytes), total ~187 MB
  char* ws = (char*)d_ws;
  unsigned short* xb   = (unsigned short*)(ws);                // [M][384] bf16 25.17 MB (yb after conv)
  unsigned short* u16  = (unsigned short*)(ws + 25165824);     // [M][384] bf16 25.17 MB
  float* xdbl = (float*)(ws + 50331648);                       // [M][64]  fp32  8.39 MB
  unsigned short* dt16 = (unsigned short*)(ws + 58720256);     // [M][384] bf16 25.17 MB
  float* Hbuf = (float*)(ws + 109051904);                      // [B][NC][D][N] 25.17 MB (h0)
  float* Sbuf = (float*)(ws + 134217728);                      // 25.17 MB
  unsigned short* zb  = (unsigned short*)(ws + 159383552);     // [M][384] bf16 25.17 MB
  unsigned short* wb  = (unsigned short*)(ws + 184549376);     // [768][192] bf16 294912 B
  unsigned short* wxb = (unsigned short*)(ws + 184844288);     // [64][384]  bf16  49152 B
  unsigned short* owb = (unsigned short*)(ws + 184893440);     // [192][384] bf16 147456 B
  float* dtwt = (float*)(ws + 185040896);                      // [12][384]  fp32  18432 B
  float* Dsum = (float*)(ws + 185059328);                      // [B][NC][384] fp32 1.57 MB
  unsigned short* yb  = xb;   // part3 output over dead xb

  // 0. weight casts/pads + dtw transpose (one kernel)
  prep_k<<<576, 256, 0, stream>>>(in_w, xw, ow, dtw, wb, wxb, owb, dtwt);
  // 1. in_proj (bf16 MFMA, XCD-swizzled, bf16 x|z outputs)
  gemm_in<<<dim3(6, 256), 256, 0, stream>>>(hs, wb, xb, zb);
  // 2. depthwise conv + SiLU (bf16 -> bf16)
  conv_silu_k<<<(MTOT * 48) / 256, 256, 0, stream>>>(xb, cw, cb, u16);
  // 3. x_proj with fused dt_proj epilogue (bit-identical dt16)
  xproj_dt<<<MTOT / 64, 256, 0, stream>>>(u16, wxb, dtwt, dtb, xdbl, dt16);
  // 4. chunked selective scan (R14-proven structure, CH=32)
  scan_part1<<<dim3(NC, BATCH), 384, 0, stream>>>(dt16, u16, xdbl, alog, Dsum, Sbuf);
  scan_part2<<<(BATCH * DINNER * DSTATE) / 256, 256, 0, stream>>>(Dsum, Sbuf, alog, Hbuf);
  scan_part3<<<dim3(NC, BATCH), 384, 0, stream>>>(dt16, u16, xdbl, alog, dsk, zb, Hbuf, yb);
  // 5. out_proj (bf16 MFMA, XCD-swizzled)
  gemm_out<<<dim3(3, 256), 256, 0, stream>>>(yb, owb, out);
}